// Round 11
// baseline (359.558 us; speedup 1.0000x reference)
//
#include <hip/hip_runtime.h>

typedef unsigned short u16;
typedef __attribute__((ext_vector_type(8))) short short8;
typedef __attribute__((ext_vector_type(4))) float f32x4;
typedef __attribute__((ext_vector_type(8))) unsigned short ushort8;
typedef __attribute__((ext_vector_type(4))) unsigned short ushort4v;

__device__ __forceinline__ u16 f2bf(float f) {
    unsigned int u = __float_as_uint(f);
    u += 0x7FFFu + ((u >> 16) & 1u);   // round-to-nearest-even
    return (u16)(u >> 16);
}
__device__ __forceinline__ float bf2f(u16 h) {
    return __uint_as_float(((unsigned int)h) << 16);
}

__device__ __forceinline__ void gld_lds16(const void* g, void* l) {
    __builtin_amdgcn_global_load_lds(
        (const __attribute__((address_space(1))) unsigned int*)g,
        (__attribute__((address_space(3))) unsigned int*)l,
        16, 0, 0);
}

#define WAITV(N)  asm volatile("s_waitcnt vmcnt(" #N ")" ::: "memory")
// raw s_barrier, OPAQUE to the compiler's waitcnt pass: no auto vmcnt(0)
// drain can be attached (the r0-r10 killer).  Side-effecting asm volatile
// cannot be reordered against gld_lds / DSR (also side-effecting).
#define ABAR()    do { asm volatile("s_barrier"); \
                       __builtin_amdgcn_sched_barrier(0); } while (0)
// rule #18: asm lgkm wait needs sched_barrier(0) or MFMA hoists past it
#define LGKM0()   do { asm volatile("s_waitcnt lgkmcnt(0)" ::: "memory"); \
                       __builtin_amdgcn_sched_barrier(0); } while (0)
// asm ds_read_b128: invisible to SIInsertWaitcnts -> no involuntary vmcnt
// ordering vs pending LDS-DMA.  RAW is OUR counted WAITV + ABAR.
#define DSR(dst, base, imm) \
    asm volatile("ds_read_b128 %0, %1 offset:%2" : "=v"(dst) : "v"(base), "n"(imm))

// ---------------------------------------------------------------------------
// C = alpha * A[M,K] * B[N,K]^T, bf16.  Tile 128x128, BK=32, 4 waves,
// 64x64 wave-tile — r10's winning base + TRIPLE-BUFFERED distance-2
// prefetch with ZERO compiler-visible drain points.
//
// WHY (r0-r10 unified): global_load_lds is an LDS *store*; the compiler
// (a) orders compiler-visible ds_reads against pending LDS-DMA and
// (b) drains vmcnt(0) before ANY compiler-visible barrier (builtin s_barrier
// included — r4 proved asm-reads-alone insufficient).  So every prior
// schedule paid ~1 exposed memory latency per K-step.  r10 (fewer, bigger
// steps) gave the only win (+10%), confirming the mechanism.  Here: asm
// ds_read + asm s_barrier + counted WAITV -> the pass has nothing to drain.
//
// Pipeline (tile t staged at iter t-2, 3 buffers, 1 barrier/iter):
//   prologue: STAGE(b0,t0); STAGE(b1,t1);            // 8 loads in flight
//   iter t:   WAITV(4) [tail: 0]   // my tile-t loads done (oldest 4)
//             ABAR                  // publish t (all waves drained); also
//                                   // WAR-guard: compute(t-1) done everywhere
//             STAGE(b[(t+2)%3], t+2)  // safe: readers of that buf were t-1
//             COMPUTE(b[t%3])         // asm ds_reads + lgkm0 + 16 MFMA
// Flight of tile t = compute(t-2)+compute(t-1)+2 barriers ~= 900-1100 cy
// >= latency -> hidden.  Outstanding invariant entering iter t: {t,t+1}=8.
//
// LDS 3 x (8KB A + 8KB B) = 48 KB -> 3 blocks/CU (VGPR ~84 like r10).
// Swizzle/staging = r0's verified map, unchanged.
// Tripwire: WRITE_SIZE ~74 MB, conflicts ~0.
//
// MODE 0: fused QKV. grid 2304.  MODE 1: logits, grid 2048 (batch=xcd).
// MODE 2: out = A V, grid 768.  (identical decomposition to r0/r10)
// ---------------------------------------------------------------------------
template <int MODE>
__global__ __launch_bounds__(256) void gemm_bt(
    const u16* __restrict__ A, const u16* __restrict__ B,
    void* __restrict__ O0, void* __restrict__ O1, void* __restrict__ O2,
    float alpha)
{
    constexpr int K   = (MODE == 2) ? 2048 : 768;
    constexpr int lda = (MODE == 2) ? 2048 : 768;
    constexpr int ldb = (MODE == 2) ? 2048 : 768;

    __shared__ __align__(16) u16 As[3 * 4096];   // 3 buffers x 8 KB
    __shared__ __align__(16) u16 Bs[3 * 4096];

    const int f = blockIdx.x;
    const int xcd = f & 7;
    const int u = f >> 3;

    int tm, bn, cn, which = 0;
    long aoff = 0, boff = 0;
    if constexpr (MODE == 0) {
        const int c = u >> 4;            // 0..17
        const int rl = u & 15;
        tm = (xcd * 16 + rl) * 128;
        bn = c * 128;
        which = c / 6;
        cn = (c % 6) * 128;
    } else if constexpr (MODE == 1) {
        const int p = u >> 6, t = u & 63, c = t >> 2, rl = t & 3;
        tm = (p * 4 + rl) * 128;
        bn = cn = c * 128;
        aoff = (long)xcd * 2048 * 768;
        boff = aoff;
    } else {
        const int p = u / 12, t = u % 12, c = t >> 1, rl = t & 1;
        tm = (p * 2 + rl) * 128;
        bn = cn = c * 128;
        aoff = (long)xcd * 2048 * 2048;
        boff = (long)xcd * 768 * 2048;
    }

    const u16* Ab = A + aoff;
    const u16* Bb = B + boff;

    const int tid  = threadIdx.x;
    const int lane = tid & 63;
    const int wave = tid >> 6;
    const int wr = wave >> 1;
    const int wc = wave & 1;

    f32x4 acc[4][4] = {};

    // --- staging (r0-verified): slot s holds chunk (row=s>>2, kc=(s&3)^((row>>1)&3))
    const int s0 = tid, s1 = tid + 256;
    const int r0_ = s0 >> 2, kc0 = (s0 & 3) ^ ((r0_ >> 1) & 3);
    const int r1_ = s1 >> 2, kc1 = (s1 & 3) ^ ((r1_ >> 1) & 3);
    const long ar0 = (long)(tm + r0_) * lda + kc0 * 8;
    const long ar1 = (long)(tm + r1_) * lda + kc1 * 8;
    const long br0 = (long)(bn + r0_) * ldb + kc0 * 8;
    const long br1 = (long)(bn + r1_) * ldb + kc1 * 8;

// BO in u16 units: 0 / 4096 / 8192
#define STAGE(BO, K0) do { \
    gld_lds16(Ab + ar0 + (K0), (void*)(As + (BO) + s0 * 8)); \
    gld_lds16(Ab + ar1 + (K0), (void*)(As + (BO) + s1 * 8)); \
    gld_lds16(Bb + br0 + (K0), (void*)(Bs + (BO) + s0 * 8)); \
    gld_lds16(Bb + br1 + (K0), (void*)(Bs + (BO) + s1 * 8)); \
} while (0)

    // --- fragment read bases as LDS byte addresses (asm DSR) ---
    const unsigned aLds = (unsigned)(unsigned long long)(&As[0]);
    const unsigned bLds = (unsigned)(unsigned long long)(&Bs[0]);
    const int swz = ((lane >> 4) ^ ((lane >> 1) & 3)) * 8;   // r0-verified
    const unsigned a_b = aLds + 2u * ((wr * 64 + (lane & 15)) * 32 + swz);
    const unsigned b_b = bLds + 2u * ((wc * 64 + (lane & 15)) * 32 + swz);

// frag i: +i*16 rows * 32 u16 = 1024 B.  imm <= 16384+3072 < 64K.
#define COMPUTE(BO) do { \
    short8 a[4], b[4]; \
    DSR(a[0], a_b, (BO) * 2 + 0);    DSR(a[1], a_b, (BO) * 2 + 1024); \
    DSR(a[2], a_b, (BO) * 2 + 2048); DSR(a[3], a_b, (BO) * 2 + 3072); \
    DSR(b[0], b_b, (BO) * 2 + 0);    DSR(b[1], b_b, (BO) * 2 + 1024); \
    DSR(b[2], b_b, (BO) * 2 + 2048); DSR(b[3], b_b, (BO) * 2 + 3072); \
    LGKM0(); \
    _Pragma("unroll") \
    for (int i = 0; i < 4; ++i) \
    _Pragma("unroll") \
        for (int j = 0; j < 4; ++j) \
            acc[i][j] = __builtin_amdgcn_mfma_f32_16x16x32_bf16( \
                a[i], b[j], acc[i][j], 0, 0, 0); \
} while (0)

// one iteration of the pipeline (K0 = this tile's k; BOC = its buffer,
// BON = buffer of tile t+2).  Uniform branches only.
#define ITER(K0, BOC, BON) do { \
    if ((K0) + 32 < K) { WAITV(4); } else { WAITV(0); } \
    ABAR(); \
    if ((K0) + 64 < K) STAGE(BON, (K0) + 64); \
    COMPUTE(BOC); \
} while (0)

    // prologue: tiles 0,1 -> buffers 0,1 (8 loads in flight)
    STAGE(0, 0);
    STAGE(4096, 32);

    int kb = 0;
#pragma unroll 1
    for (; kb + 96 <= K; kb += 96) {
        ITER(kb,      0,    8192);   // t%3==0, stages (t+2)%3==2
        ITER(kb + 32, 4096, 0);      // t%3==1, stages 0
        ITER(kb + 64, 8192, 4096);   // t%3==2, stages 1
    }
    if (kb < K)                      // K%96==32 (MODE 2): tile 63, buf 0
        ITER(kb, 0, 8192);

#undef ITER
#undef COMPUTE
#undef STAGE

    // Epilogue. C/D layout: col = lane&15, row = (lane>>4)*4 + r
#pragma unroll
    for (int i = 0; i < 4; ++i) {
        const int row0 = tm + wr * 64 + i * 16 + ((lane >> 4) << 2);
#pragma unroll
        for (int j = 0; j < 4; ++j) {
            const int col = cn + wc * 64 + j * 16 + (lane & 15);
#pragma unroll
            for (int r = 0; r < 4; ++r) {
                const int row = row0 + r;
                const float val = acc[i][j][r] * alpha;
                if constexpr (MODE == 0) {
                    if (which == 0)
                        ((u16*)O0)[(long)row * 768 + col] = f2bf(val);
                    else if (which == 1)
                        ((u16*)O1)[(long)row * 768 + col] = f2bf(val);
                    else  // V^T: [b, col, s]
                        ((u16*)O2)[((long)(row >> 11) * 768 + col) * 2048 + (row & 2047)] = f2bf(val);
                } else if constexpr (MODE == 1) {
                    ((u16*)O0)[(long)xcd * 2048 * 2048 + (long)row * 2048 + col] = f2bf(val);
                } else {
                    ((float*)O0)[(long)xcd * 2048 * 768 + (long)row * 768 + col] = val;
                }
            }
        }
    }
}

// ---------------------------------------------------------------------------
__global__ __launch_bounds__(256) void cvt_x_kernel(
    const float4* __restrict__ x, ushort4v* __restrict__ out, int n4)
{
    int i = blockIdx.x * 256 + threadIdx.x;
    if (i < n4) {
        float4 f = x[i];
        ushort4v o;
        o.x = f2bf(f.x); o.y = f2bf(f.y); o.z = f2bf(f.z); o.w = f2bf(f.w);
        out[i] = o;
    }
}

// w[3][768][768] (m,d,o)  ->  wt[3][768][768] (m,o,d), bf16
__global__ __launch_bounds__(256) void cvt_w_kernel(
    const float* __restrict__ w, u16* __restrict__ wt)
{
    int i = blockIdx.x * 256 + threadIdx.x;   // total 3*768*768
    int d = i % 768;
    int o = (i / 768) % 768;
    int m = i / (768 * 768);
    wt[i] = f2bf(w[((long)m * 768 + d) * 768 + o]);
}

// one block per row, 2048 bf16 logits in-place -> softmax probs (bf16)
__global__ __launch_bounds__(256) void softmax_kernel(u16* __restrict__ S)
{
    const long row = blockIdx.x;
    u16* p = S + row * 2048;
    const int t = threadIdx.x;
    const int lane = t & 63;
    const int wave = t >> 6;
    __shared__ float red[8];

    ushort8 raw = *(const ushort8*)(p + t * 8);
    float v[8];
    float m = -1e30f;
#pragma unroll
    for (int i = 0; i < 8; ++i) { v[i] = bf2f(raw[i]); m = fmaxf(m, v[i]); }
#pragma unroll
    for (int off = 1; off < 64; off <<= 1) m = fmaxf(m, __shfl_xor(m, off, 64));
    if (lane == 0) red[wave] = m;
    __syncthreads();
    m = fmaxf(fmaxf(red[0], red[1]), fmaxf(red[2], red[3]));

    float s = 0.f;
#pragma unroll
    for (int i = 0; i < 8; ++i) { v[i] = __expf(v[i] - m); s += v[i]; }
#pragma unroll
    for (int off = 1; off < 64; off <<= 1) s += __shfl_xor(s, off, 64);
    if (lane == 0) red[4 + wave] = s;
    __syncthreads();
    s = (red[4] + red[5]) + (red[6] + red[7]);

    const float inv = 1.0f / s;
    ushort8 out;
#pragma unroll
    for (int i = 0; i < 8; ++i) out[i] = f2bf(v[i] * inv);
    *(ushort8*)(p + t * 8) = out;
}

// ---------------------------------------------------------------------------
extern "C" void kernel_launch(void* const* d_in, const int* in_sizes, int n_in,
                              void* d_out, int out_size, void* d_ws, size_t ws_size,
                              hipStream_t stream)
{
    const float* x  = (const float*)d_in[0];   // [8,2048,768]
    const float* wk = (const float*)d_in[1];   // [3,768,768]
    float* out = (float*)d_out;                // [8,2048,768]

    char* ws = (char*)d_ws;
    u16* xbf = (u16*)(ws);                       // 16384x768        25.2 MB
    u16* wt  = (u16*)(ws + 25165824);            // 3x768x768 (W^T)   3.5 MB
    u16* qbf = (u16*)(ws + 28704768);            // 16384x768        25.2 MB
    u16* kbf = (u16*)(ws + 53870592);            // 16384x768        25.2 MB
    u16* vt  = (u16*)(ws + 79036416);            // 8x768x2048       25.2 MB
    u16* S   = (u16*)(ws + 104202240);           // 8x2048x2048      67.1 MB

    // 1. conversions
    cvt_x_kernel<<<dim3(12288), dim3(256), 0, stream>>>(
        (const float4*)x, (ushort4v*)xbf, 3145728);
    cvt_w_kernel<<<dim3(6912), dim3(256), 0, stream>>>(wk, wt);

    // 2. fused QKV projections (one dispatch, 18 col-tiles share x row-tiles)
    gemm_bt<0><<<dim3(2304), dim3(256), 0, stream>>>(
        xbf, wt, qbf, kbf, vt, 1.0f);

    // 3. logits: S_b = 0.125 * Q_b K_b^T   (batch <-> XCD)
    gemm_bt<1><<<dim3(2048), dim3(256), 0, stream>>>(
        qbf, kbf, S, nullptr, nullptr, 0.125f);

    // 4. softmax rows (in place, bf16)
    softmax_kernel<<<dim3(16384), dim3(256), 0, stream>>>(S);

    // 5. out_b = A_b V_b
    gemm_bt<2><<<dim3(768), dim3(256), 0, stream>>>(
        S, vt, out, nullptr, nullptr, 1.0f);
}